// Round 11
// baseline (159.921 us; speedup 1.0000x reference)
//
#include <hip/hip_runtime.h>
#include <hip/hip_bf16.h>

// ---------------------------------------------------------------------------
// Naive3DConvEncoder: scatter+wtrans+fcw -> conv12(grid->c2, fused MFMA)
//                      -> conv3(MFMA) -> fc(MFMA, atomic epilogue).
// B=32, N=16384, G=64.  conv1 is FUSED into conv2: each conv2 block stages a
// 7x67x35 binary-grid slab (16.4 KB LDS), computes its 3x33x17x16ch c1 slab
// in-register (fp32->relu->bf16, identical numerics to the old conv1 kernel),
// writes the same y-parity A-slab layout, then runs the old MFMA K-loop.
// Deletes: conv1 kernel, 33.5 MB c1b write + 33.5 MB read.
// ws layout:
//   grid_u8 : 0           (8,388,608 B)
//   c2b     : 75,497,472  (8,388,608 B bf16 [b][z][y][x][c32])
//   featb   : 92,274,688  (2,097,152 B bf16 [b][f])
//   w2b     : 98,566,144  (28,672 B bf16 [28 sh][32 oc][16 c])
//   w3b     : 98,697,216  (110,592 B bf16 [27 sh][64 oc][32 c])
//   fc_wb   : 98,807,808  (8,388,608 B bf16 [l][32768])
// ---------------------------------------------------------------------------

typedef __attribute__((ext_vector_type(8))) short bf16x8;
typedef __attribute__((ext_vector_type(4))) float f32x4;

__device__ inline unsigned short f2bf(float f) {
    __hip_bfloat16 h = __float2bfloat16(f);
    return *reinterpret_cast<unsigned short*>(&h);
}

// Fused: blocks 0..2047 scatter; 2048..2319 w2/w3 transpose; 2320..4367 fc_w->bf16.
__global__ void k_scatter_wtrans(const float* __restrict__ coords,
                                 unsigned char* __restrict__ grid,
                                 const float* __restrict__ w2,
                                 unsigned short* __restrict__ w2b,
                                 const float* __restrict__ w3,
                                 unsigned short* __restrict__ w3b,
                                 const float* __restrict__ fc_w,
                                 unsigned short* __restrict__ fc_wb) {
    int blk = blockIdx.x;
    if (blk < 2048) {
        int i = blk * 256 + threadIdx.x;             // 524288 threads
        float cx = coords[3 * i + 0];
        float cy = coords[3 * i + 1];
        float cz = coords[3 * i + 2];
        int ix = (int)((cx + 1.0f) * 0.5f * 63.0f);
        int iy = (int)((cy + 1.0f) * 0.5f * 63.0f);
        int iz = (int)((cz + 1.0f) * 0.5f * 63.0f);
        ix = min(max(ix, 0), 63);
        iy = min(max(iy, 0), 63);
        iz = min(max(iz, 0), 63);
        int b = i >> 14;
        grid[((b * 64 + iz) * 64 + iy) * 64 + ix] = 1;
    } else if (blk < 2320) {
        int i = (blk - 2048) * 256 + threadIdx.x;    // 0..69631
        if (i < 14336) {
            int sh = i >> 9, oc = (i >> 4) & 31, c = i & 15;
            float v = (sh < 27) ? w2[oc * 432 + c * 27 + sh] : 0.0f;
            w2b[i] = f2bf(v);
        } else {
            int j = i - 14336;
            if (j < 55296) {
                int sh = j >> 11, oc = (j >> 5) & 63, c = j & 31;
                w3b[j] = f2bf(w3[oc * 864 + c * 27 + sh]);
            }
        }
    } else {
        int u = (blk - 2320) * 256 + threadIdx.x;    // 0..524287, 8 elems each
        const float* src = fc_w + (size_t)u * 8;
        float4 lo = *(const float4*)src;
        float4 hi = *(const float4*)(src + 4);
        unsigned int dw[4];
        dw[0] = (unsigned int)f2bf(lo.x) | ((unsigned int)f2bf(lo.y) << 16);
        dw[1] = (unsigned int)f2bf(lo.z) | ((unsigned int)f2bf(lo.w) << 16);
        dw[2] = (unsigned int)f2bf(hi.x) | ((unsigned int)f2bf(hi.y) << 16);
        dw[3] = (unsigned int)f2bf(hi.z) | ((unsigned int)f2bf(hi.w) << 16);
        *(int4*)(fc_wb + (size_t)u * 8) = int4{(int)dw[0], (int)dw[1], (int)dw[2], (int)dw[3]};
    }
}

// ---------------------------------------------------------------------------
// conv12: fused conv1+conv2 implicit GEMM. block=(b,zo,xh), M=128, N=32 oc.
// Phase 1: stage 7x67x9-dword grid slab (zero-filled at z<0 / y<0 / x<0).
// Phase 2: compute c1 slab (3x33x17 voxels x 16ch) -> A-slab bf16 (y-parity
//          layout, row stride 560 B). slab indices provably in-range.
// Phase 3: the r10 MFMA K-loop + epilogue, unchanged.
// LDS: 16,896 (gslab) + 55,440 (A-slab) = 72,336 B -> 2 blocks/CU.
// ---------------------------------------------------------------------------
__device__ constexpr int abase2(int sh) {
    return (sh / 9) * 18480 + (((sh % 9) / 3) & 1) * 9520 +
           (((sh % 9) / 3) >> 1) * 560 + (sh % 3) * 32;
}

__global__ __launch_bounds__(512, 4) void k_conv12_mfma(
        const unsigned char* __restrict__ grid,
        const float* __restrict__ w1,
        const float* __restrict__ b1,
        const unsigned short* __restrict__ w2b,
        const float* __restrict__ b2,
        unsigned short* __restrict__ c2b) {
    __shared__ __align__(16) unsigned int gslab[4224];   // 7*67*9=4221 dwords
    __shared__ __align__(16) char smem[55440];
    const int t = threadIdx.x;
    const int b = blockIdx.x >> 5;
    const int zo = (blockIdx.x >> 1) & 15;
    const int xh = blockIdx.x & 1;
    const int lane = t & 63;
    const int wid = t >> 6;                          // 8 waves

    // Phase 1: grid slab. gz in [4zo-3, 4zo+3], gy in [-3,63], gx base 32xh-4.
    {
        const unsigned char* gb = grid + b * 262144;
        const int gz0 = 4 * zo - 3;
        for (int i = t; i < 4221; i += 512) {
            int gz = i / 603, rem = i - gz * 603;
            int gy = rem / 9, d = rem - gy * 9;
            int z = gz0 + gz, y = gy - 3, x4 = 32 * xh - 4 + 4 * d;
            unsigned int v = 0;
            if ((z >= 0) & (y >= 0) & (x4 >= 0))
                v = *(const unsigned int*)(gb + (z * 64 + y) * 64 + x4);
            gslab[i] = v;
        }
    }
    __syncthreads();

    // Phase 2: compute c1 voxels (kz, iy_st, c) -> A-slab.
    {
        const unsigned char* gs = (const unsigned char*)gslab;
        for (int i = t; i < 1683; i += 512) {
            int kz = i / 561, rem = i - kz * 561;
            int iy_st = rem / 17, c = rem - iy_st * 17;
            char* dstp = smem + kz * 18480 + (iy_st & 1) * 9520 +
                         (iy_st >> 1) * 560 + c * 32;
            int iz = 2 * zo + kz - 1, iy = iy_st - 1, ix = 16 * xh + c - 1;
            if ((iz | iy | ix) < 0) {
                *(int4*)dstp = int4{0, 0, 0, 0};
                *(int4*)(dstp + 16) = int4{0, 0, 0, 0};
                continue;
            }
            float acc[16];
#pragma unroll
            for (int ch = 0; ch < 16; ++ch) acc[ch] = b1[ch];
            const int sz0 = 2 * kz, sy0 = 2 * iy_st, sx0 = 2 * c + 1;
#pragma unroll
            for (int kz2 = 0; kz2 < 3; ++kz2)
#pragma unroll
                for (int ky2 = 0; ky2 < 3; ++ky2)
#pragma unroll
                    for (int kx2 = 0; kx2 < 3; ++kx2) {
                        float fg = (float)gs[((sz0 + kz2) * 67 + sy0 + ky2) * 36 +
                                             sx0 + kx2];
                        const int t27 = kz2 * 9 + ky2 * 3 + kx2;
#pragma unroll
                        for (int ch = 0; ch < 16; ++ch)
                            acc[ch] = fmaf(w1[ch * 27 + t27], fg, acc[ch]);
                    }
            unsigned int dw[8];
#pragma unroll
            for (int j = 0; j < 8; ++j) {
                unsigned short lo = f2bf(fmaxf(acc[2 * j], 0.0f));
                unsigned short hi = f2bf(fmaxf(acc[2 * j + 1], 0.0f));
                dw[j] = (unsigned int)lo | ((unsigned int)hi << 16);
            }
            *(int4*)dstp = int4{(int)dw[0], (int)dw[1], (int)dw[2], (int)dw[3]};
            *(int4*)(dstp + 16) = int4{(int)dw[4], (int)dw[5], (int)dw[6], (int)dw[7]};
        }
    }
    __syncthreads();

    // Phase 3: MFMA K-loop (identical to r10 conv2).
    const int y16 = lane & 15;
    const int g = lane >> 4;
    const int h = g & 1;
    const int s = g >> 1;
    const int laneA = y16 * 560 + h * 16;
    const int laneB = (lane & 15) * 32 + h * 16 + s * 1024;
    const int xl64 = wid * 64;
    const char* wbase = (const char*)w2b;

    f32x4 acc0 = {0, 0, 0, 0}, acc1 = {0, 0, 0, 0};

#pragma unroll
    for (int sp = 0; sp < 14; ++sp) {
        const int sh0 = 2 * sp;
        const int sh1 = (2 * sp + 1 < 27) ? 2 * sp + 1 : 26;
        const int a0 = abase2(sh0);
        const int d01 = abase2(sh1) - a0;
        bf16x8 A = *(const bf16x8*)(smem + laneA + a0 + (s ? d01 : 0) + xl64);
        const char* wb = wbase + sp * 2048 + laneB;
        bf16x8 B0 = *(const bf16x8*)wb;
        bf16x8 B1 = *(const bf16x8*)(wb + 512);
        acc0 = __builtin_amdgcn_mfma_f32_16x16x32_bf16(A, B0, acc0, 0, 0, 0);
        acc1 = __builtin_amdgcn_mfma_f32_16x16x32_bf16(A, B1, acc1, 0, 0, 0);
    }

    __syncthreads();
    float* sOut = (float*)smem;                      // [32 oc][129]
    {
        int ocl = lane & 15;
        int yb = (lane >> 4) * 4;
#pragma unroll
        for (int r = 0; r < 4; ++r) {
            sOut[ocl * 129        + (yb + r) * 8 + wid] = acc0[r];
            sOut[(ocl + 16) * 129 + (yb + r) * 8 + wid] = acc1[r];
        }
    }
    __syncthreads();
    {
        int vox = t >> 2, q = t & 3;
        unsigned int dw[4];
#pragma unroll
        for (int j = 0; j < 4; ++j) {
            int oc0 = 8 * q + 2 * j;
            float v0 = fmaxf(sOut[oc0 * 129 + vox] + b2[oc0], 0.0f);
            float v1 = fmaxf(sOut[(oc0 + 1) * 129 + vox] + b2[oc0 + 1], 0.0f);
            dw[j] = (unsigned int)f2bf(v0) | ((unsigned int)f2bf(v1) << 16);
        }
        char* dst = (char*)c2b +
                    ((size_t)b * 4096 + zo * 256 + (vox >> 3) * 16 + xh * 8 + (vox & 7)) * 64 +
                    q * 16;
        *(int4*)dst = int4{(int)dw[0], (int)dw[1], (int)dw[2], (int)dw[3]};
    }
}

// ---------------------------------------------------------------------------
// conv3 implicit GEMM (x-parity-split voxels); epilogue -> featb bf16.
// ---------------------------------------------------------------------------
__global__ __launch_bounds__(512) void k_conv3_mfma(
        const unsigned short* __restrict__ c2b,
        const unsigned short* __restrict__ w3b,
        const float* __restrict__ b3,
        unsigned short* __restrict__ featb) {
    __shared__ __align__(16) char smem[55488];
    const int t = threadIdx.x;
    const int b = blockIdx.x >> 3;
    const int zo = blockIdx.x & 7;
    const int lane = t & 63;
    const int wid = t >> 6;

    if (t < 396) {
        int p3 = t / 132, j = t % 132;
        int v = j >> 2, g = j & 3;
        int iy_st = (v < 17) ? 0 : (v - 16);
        int ix_st = (v < 17) ? v : 0;
        int ux = (ix_st & 1) ? 9 + (ix_st >> 1) : (ix_st >> 1);
        int u = (p3 * 17 + iy_st) * 17 + ux;
        *(int4*)(smem + u * 64 + g * 16) = int4{0, 0, 0, 0};
    }

    const char* src = (const char*)c2b + (size_t)b * 262144;
#pragma unroll
    for (int r = 0; r < 6; ++r) {
        int i = r * 512 + t;
        int g = i & 3, vox = i >> 2;
        int kz = vox >> 8, pos = vox & 255;
        int iy = pos >> 4, ix = pos & 15;
        int iz = 2 * zo + kz - 1;
        int4 v = {0, 0, 0, 0};
        if (iz >= 0)
            v = *(const int4*)(src + ((size_t)(iz * 256 + pos)) * 64 + g * 16);
        int ix_st = ix + 1;
        int ux = (ix_st & 1) ? 9 + (ix_st >> 1) : (ix_st >> 1);
        int u = (kz * 17 + iy + 1) * 17 + ux;
        *(int4*)(smem + u * 64 + g * 16) = v;
    }
    __syncthreads();

    const int mt = wid >> 1;
    const int ntp = wid & 1;
    const int m = mt * 16 + (lane & 15);
    const int y = m >> 3, x = m & 7;
    const int g = lane >> 4;
    const int laneA = (34 * y + x) * 64 + g * 16;
    const char* wb_base = (const char*)w3b + (ntp * 32 + (lane & 15)) * 64 + g * 16;

    f32x4 acc0 = {0, 0, 0, 0}, acc1 = {0, 0, 0, 0};

#pragma unroll
    for (int sh = 0; sh < 27; ++sh) {
        const int kz = sh / 9, ky = (sh % 9) / 3, kx = sh % 3;
        const int uxc = (kx == 0) ? 0 : ((kx == 1) ? 9 : 1);
        const int aoff = (289 * kz + 17 * ky + uxc) * 64;
        bf16x8 A = *(const bf16x8*)(smem + laneA + aoff);
        const char* wb = wb_base + sh * 4096;
        bf16x8 B0 = *(const bf16x8*)wb;
        bf16x8 B1 = *(const bf16x8*)(wb + 1024);
        acc0 = __builtin_amdgcn_mfma_f32_16x16x32_bf16(A, B0, acc0, 0, 0, 0);
        acc1 = __builtin_amdgcn_mfma_f32_16x16x32_bf16(A, B1, acc1, 0, 0, 0);
    }

    __syncthreads();
    float* sOut = (float*)smem;                      // [64 oc][65]
    {
        int ocl = lane & 15;
        int mb = mt * 16 + (lane >> 4) * 4;
#pragma unroll
        for (int r = 0; r < 4; ++r) {
            sOut[(ntp * 32 + ocl) * 65 + mb + r]      = acc0[r];
            sOut[(ntp * 32 + 16 + ocl) * 65 + mb + r] = acc1[r];
        }
    }
    __syncthreads();
    {
        int oc = t >> 3, q = t & 7;
        float bb = b3[oc];
        unsigned int dw[4];
#pragma unroll
        for (int j = 0; j < 4; ++j) {
            float v0 = fmaxf(sOut[oc * 65 + q * 8 + 2 * j] + bb, 0.0f);
            float v1 = fmaxf(sOut[oc * 65 + q * 8 + 2 * j + 1] + bb, 0.0f);
            dw[j] = (unsigned int)f2bf(v0) | ((unsigned int)f2bf(v1) << 16);
        }
        char* dst = (char*)featb + (size_t)b * 65536 + oc * 1024 + zo * 128 + q * 16;
        *(int4*)dst = int4{(int)dw[0], (int)dw[1], (int)dw[2], (int)dw[3]};
    }
}

// ---------------------------------------------------------------------------
// FC on MFMA: out(32,128) = featb(32,32768) @ fc_wb^T + fc_b.
// ---------------------------------------------------------------------------
__global__ __launch_bounds__(256) void k_fc_mfma(
        const unsigned short* __restrict__ featb,
        const unsigned short* __restrict__ fc_wb,
        const float* __restrict__ fc_b,
        float* __restrict__ out) {
    __shared__ __align__(16) char smem[32 * 272];    // 8,704 B
    const int t = threadIdx.x;
    const int blk = blockIdx.x;                      // 256
    const int f0 = blk << 7;                         // f-chunk of 128

    {
        int b = t >> 3, seg = t & 7;                 // 32 B per thread
        const char* gp = (const char*)featb + (size_t)b * 65536 + f0 * 2 + seg * 32;
        char* d = smem + b * 272 + seg * 32;
        *(int4*)d = *(const int4*)gp;
        *(int4*)(d + 16) = *(const int4*)(gp + 16);
    }
    __syncthreads();

    const int lane = t & 63;
    const int w = t >> 6;                            // 4 waves -> l-tiles {2w,2w+1}
    const int n = lane & 15;
    const int g = lane >> 4;

    f32x4 acc00 = {0, 0, 0, 0}, acc01 = {0, 0, 0, 0};
    f32x4 acc10 = {0, 0, 0, 0}, acc11 = {0, 0, 0, 0};

    const char* wb0 = (const char*)fc_wb + ((size_t)(2 * w * 16 + n)) * 65536 + f0 * 2 + g * 16;
    const char* wb1 = wb0 + 16 * 65536;

#pragma unroll
    for (int ks = 0; ks < 4; ++ks) {
        bf16x8 A0 = *(const bf16x8*)(smem + n * 272 + ks * 64 + g * 16);
        bf16x8 A1 = *(const bf16x8*)(smem + (16 + n) * 272 + ks * 64 + g * 16);
        bf16x8 B0 = *(const bf16x8*)(wb0 + ks * 64);
        bf16x8 B1 = *(const bf16x8*)(wb1 + ks * 64);
        acc00 = __builtin_amdgcn_mfma_f32_16x16x32_bf16(A0, B0, acc00, 0, 0, 0);
        acc10 = __builtin_amdgcn_mfma_f32_16x16x32_bf16(A1, B0, acc10, 0, 0, 0);
        acc01 = __builtin_amdgcn_mfma_f32_16x16x32_bf16(A0, B1, acc01, 0, 0, 0);
        acc11 = __builtin_amdgcn_mfma_f32_16x16x32_bf16(A1, B1, acc11, 0, 0, 0);
    }

    const int bo = (lane >> 4) * 4;
    const int l0 = 2 * w * 16 + (lane & 15);
    const int l1 = l0 + 16;
    const bool bias = (blk == 0);
    const float bb0 = bias ? fc_b[l0] : 0.0f;
    const float bb1 = bias ? fc_b[l1] : 0.0f;
#pragma unroll
    for (int r = 0; r < 4; ++r) {
        atomicAdd(&out[(bo + r) * 128 + l0],      acc00[r] + bb0);
        atomicAdd(&out[(bo + r + 16) * 128 + l0], acc10[r] + bb0);
        atomicAdd(&out[(bo + r) * 128 + l1],      acc01[r] + bb1);
        atomicAdd(&out[(bo + r + 16) * 128 + l1], acc11[r] + bb1);
    }
}

extern "C" void kernel_launch(void* const* d_in, const int* in_sizes, int n_in,
                              void* d_out, int out_size, void* d_ws, size_t ws_size,
                              hipStream_t stream) {
    const float* coords = (const float*)d_in[0];
    const float* w1 = (const float*)d_in[1];
    const float* b1 = (const float*)d_in[2];
    const float* w2 = (const float*)d_in[3];
    const float* b2 = (const float*)d_in[4];
    const float* w3 = (const float*)d_in[5];
    const float* b3 = (const float*)d_in[6];
    const float* fc_w = (const float*)d_in[7];
    const float* fc_b = (const float*)d_in[8];

    unsigned char* grid_u8 = (unsigned char*)d_ws;
    unsigned short* c2b = (unsigned short*)((char*)d_ws + 75497472);
    unsigned short* featb = (unsigned short*)((char*)d_ws + 92274688);
    unsigned short* w2b = (unsigned short*)((char*)d_ws + 98566144);
    unsigned short* w3b = (unsigned short*)((char*)d_ws + 98697216);
    unsigned short* fc_wb = (unsigned short*)((char*)d_ws + 98807808);
    float* out = (float*)d_out;

    hipMemsetAsync(grid_u8, 0, 8388608, stream);
    hipMemsetAsync(out, 0, 32 * 128 * sizeof(float), stream);

    k_scatter_wtrans<<<4368, 256, 0, stream>>>(coords, grid_u8, w2, w2b, w3, w3b,
                                               fc_w, fc_wb);
    k_conv12_mfma<<<1024, 512, 0, stream>>>(grid_u8, w1, b1, w2b, b2, c2b);
    k_conv3_mfma<<<256, 512, 0, stream>>>(c2b, w3b, b3, featb);
    k_fc_mfma<<<256, 256, 0, stream>>>(featb, fc_wb, fc_b, out);
}